// Round 14
// baseline (461.597 us; speedup 1.0000x reference)
//
#include <hip/hip_runtime.h>
#include <hip/hip_bf16.h>

#define NUSERS  50000
#define NNODES  100000
#define NEDGES  3200000
#define DIM     64
#define OSTRIDE 256   // output row stride: (3+1)*64
#define NBUCK   391   // ceil(NNODES/256): 256-row buckets
#define EPB_C   2048  // edges per block: count (read-only, wants occupancy)
#define NPBLK_C 1563
#define EPB_P   4096  // edges per block: place (LDS-staged, 45KB)
#define NPBLK_P 782
#define NCOLB   391   // col>>8 bins (100000>>8 = 390 max)

typedef unsigned short u16;
typedef unsigned int u32;
typedef __attribute__((ext_vector_type(8))) short bf16x8;
typedef __attribute__((ext_vector_type(4))) float f32x4;

__device__ __forceinline__ float us2f(u16 u) {
    return __uint_as_float((u32)u << 16);
}
__device__ __forceinline__ u16 f2b(float f) {           // f32 -> bf16 RNE bits
    u32 u = __float_as_uint(f);
    return (u16)((u + 0x7fffu + ((u >> 16) & 1u)) >> 16);
}

// ---------------------------------------------------------------------------
// out[:, 0:64] = concat(ue, ie) (fp32); ego[N][64] bf16
// ---------------------------------------------------------------------------
__global__ __launch_bounds__(256) void init_ego(const float* __restrict__ ue,
                                                const float* __restrict__ ie,
                                                float* __restrict__ out,
                                                u32*   __restrict__ ego32) {
    int gid = blockIdx.x * 256 + threadIdx.x;
    if (gid >= NNODES * 16) return;
    int node = gid >> 4, c = gid & 15;
    float4 v = (node < NUSERS)
        ? ((const float4*)ue)[node * 16 + c]
        : ((const float4*)ie)[(size_t)(node - NUSERS) * 16 + c];
    ((float4*)(out + (size_t)node * OSTRIDE))[c] = v;
    u32* d = ego32 + (size_t)node * 32 + 2 * c;
    d[0] = (u32)f2b(v.x) | ((u32)f2b(v.y) << 16);
    d[1] = (u32)f2b(v.z) | ((u32)f2b(v.w) << 16);
}

// ---------------------------------------------------------------------------
// Pass 1a: bucket histogram (row>>8). EPB 2048 for occupancy (read-only).
// ---------------------------------------------------------------------------
__global__ __launch_bounds__(256) void bucket_count(const int* __restrict__ rows,
                                                    int* __restrict__ bcount) {
    __shared__ int lh[NBUCK];
    int tid = threadIdx.x;
    for (int i = tid; i < NBUCK; i += 256) lh[i] = 0;
    __syncthreads();
    int e0 = blockIdx.x * EPB_C, e1 = min(e0 + EPB_C, NEDGES);
    for (int e = e0 + tid; e < e1; e += 256)
        atomicAdd(&lh[rows[e] >> 8], 1);
    __syncthreads();
    for (int i = tid; i < NBUCK; i += 256)
        if (lh[i]) atomicAdd(&bcount[i], lh[i]);
}

__global__ __launch_bounds__(512) void bucket_scan(const int* __restrict__ bcount,
                                                   int* __restrict__ bbase,
                                                   int* __restrict__ bcursor) {
    __shared__ int sc[512];
    int tid = threadIdx.x;
    int v = (tid < NBUCK) ? bcount[tid] : 0;
    sc[tid] = v;
    __syncthreads();
    for (int off = 1; off < 512; off <<= 1) {
        int t = (tid >= off) ? sc[tid - off] : 0;
        __syncthreads();
        sc[tid] += t;
        __syncthreads();
    }
    if (tid < NBUCK) {
        int excl = sc[tid] - v;
        bbase[tid] = excl;
        bcursor[tid] = excl;
    }
    if (tid == 0) bbase[NBUCK] = NEDGES;
}

// ---------------------------------------------------------------------------
// Pass 1b (R14): LDS-staged place. Per 4096-edge block: histogram -> local
// scan -> 1 global reservation/bucket -> scatter payload into LDS in bucket
// order -> streamed flush (consecutive lanes write consecutive addresses of
// each bucket run). Converts random 8B stores into coalesced bursts.
// ---------------------------------------------------------------------------
__global__ __launch_bounds__(256) void bucket_place(const int*   __restrict__ rows,
                                                    const int*   __restrict__ cols,
                                                    const float* __restrict__ vals,
                                                    int*  __restrict__ bcursor,
                                                    int2* __restrict__ tmp) {
    __shared__ int  cnt[NBUCK];      // histogram -> local cursor
    __shared__ int  adj[NBUCK];      // global base - local start
    __shared__ int  tsum[256];
    __shared__ int2 payload[EPB_P];  // 32 KB
    __shared__ u16  bucket_of[EPB_P];// 8 KB

    int tid = threadIdx.x;
    for (int i = tid; i < NBUCK; i += 256) cnt[i] = 0;
    __syncthreads();
    int e0 = blockIdx.x * EPB_P, e1 = min(e0 + EPB_P, NEDGES);
    for (int e = e0 + tid; e < e1; e += 256)
        atomicAdd(&cnt[rows[e] >> 8], 1);
    __syncthreads();

    // local exclusive scan over 391 bins (2 bins/thread) + global reservation
    int i0 = 2 * tid, i1 = i0 + 1;
    int c0 = (i0 < NBUCK) ? cnt[i0] : 0;
    int c1 = (i1 < NBUCK) ? cnt[i1] : 0;
    int tot = c0 + c1;
    tsum[tid] = tot;
    __syncthreads();
    for (int off = 1; off < 256; off <<= 1) {
        int t = (tid >= off) ? tsum[tid - off] : 0;
        __syncthreads();
        tsum[tid] += t;
        __syncthreads();
    }
    int run = tsum[tid] - tot;
    if (i0 < NBUCK) {
        int gb = c0 ? atomicAdd(&bcursor[i0], c0) : 0;
        adj[i0] = gb - run;
        cnt[i0] = run;
        run += c0;
    }
    if (i1 < NBUCK) {
        int gb = c1 ? atomicAdd(&bcursor[i1], c1) : 0;
        adj[i1] = gb - run;
        cnt[i1] = run;
    }
    __syncthreads();

    // scatter into LDS, bucket-ordered
    for (int e = e0 + tid; e < e1; e += 256) {
        int r = rows[e];
        int b = r >> 8;
        int q = atomicAdd(&cnt[b], 1);
        payload[q]   = make_int2(((r & 255) << 20) | cols[e], (int)f2b(vals[e]));
        bucket_of[q] = (u16)b;
    }
    __syncthreads();

    // streamed flush: consecutive slots -> consecutive global addresses/run
    int nblk = e1 - e0;
    for (int i = tid; i < nblk; i += 256) {
        int b = bucket_of[i];
        tmp[adj[b] + i] = payload[i];
    }
}

// ---------------------------------------------------------------------------
// Pass 2: within each 256-row bucket, order edges by col>>8 bin.
// ---------------------------------------------------------------------------
__global__ __launch_bounds__(256) void bucket_colsort(const int*  __restrict__ bbase,
                                                      const int2* __restrict__ tmp,
                                                      u32* __restrict__ colT,
                                                      u16* __restrict__ valT) {
    __shared__ int cnt[NCOLB];
    __shared__ int tsum[256];
    int b = blockIdx.x, tid = threadIdx.x;
    int j0 = bbase[b], j1 = bbase[b + 1];
    for (int i = tid; i < NCOLB; i += 256) cnt[i] = 0;
    __syncthreads();
    for (int j = j0 + tid; j < j1; j += 256)
        atomicAdd(&cnt[(tmp[j].x & 0xFFFFF) >> 8], 1);
    __syncthreads();
    int i0 = 2 * tid, i1 = 2 * tid + 1;
    int c0 = (i0 < NCOLB) ? cnt[i0] : 0;
    int c1 = (i1 < NCOLB) ? cnt[i1] : 0;
    int tot = c0 + c1;
    tsum[tid] = tot;
    __syncthreads();
    for (int off = 1; off < 256; off <<= 1) {
        int t = (tid >= off) ? tsum[tid - off] : 0;
        __syncthreads();
        tsum[tid] += t;
        __syncthreads();
    }
    int run = j0 + tsum[tid] - tot;
    if (i0 < NCOLB) { cnt[i0] = run; run += c0; }
    if (i1 < NCOLB) cnt[i1] = run;
    __syncthreads();
    for (int j = j0 + tid; j < j1; j += 256) {
        int2 t2 = tmp[j];
        int q = atomicAdd(&cnt[(t2.x & 0xFFFFF) >> 8], 1);
        colT[q] = (u32)t2.x;
        valT[q] = (u16)t2.y;
    }
}

// ---------------------------------------------------------------------------
// Pass 3: bin-ordered stream -> row-major CSR (per-row edges ~col-sorted)
// ---------------------------------------------------------------------------
__global__ __launch_bounds__(256) void bucket_to_csr(const int* __restrict__ bbase,
                                                     const u32* __restrict__ colT,
                                                     const u16* __restrict__ valT,
                                                     int* __restrict__ rs,
                                                     int* __restrict__ colS,
                                                     u16* __restrict__ valS) {
    __shared__ int rcnt[256];
    __shared__ int cur[256];
    int b = blockIdx.x, tid = threadIdx.x;
    int j0 = bbase[b], j1 = bbase[b + 1];
    rcnt[tid] = 0;
    __syncthreads();
    for (int j = j0 + tid; j < j1; j += 256)
        atomicAdd(&rcnt[colT[j] >> 20], 1);
    __syncthreads();
    int own = rcnt[tid];
    for (int off = 1; off < 256; off <<= 1) {
        int t = (tid >= off) ? rcnt[tid - off] : 0;
        __syncthreads();
        rcnt[tid] += t;
        __syncthreads();
    }
    int start = j0 + rcnt[tid] - own;
    int row = b * 256 + tid;
    if (row < NNODES) rs[row] = start;
    if (b == 0 && tid == 0) rs[NNODES] = NEDGES;
    cur[tid] = start;
    __syncthreads();
    for (int j = j0 + tid; j < j1; j += 256) {
        u32 cx = colT[j];
        int p = atomicAdd(&cur[cx >> 20], 1);
        colS[p] = cx & 0xFFFFF;
        valS[p] = valT[j];
    }
}

// ---------------------------------------------------------------------------
// Pre-convert weights to fragment-ordered bf16 (R7, proven)
// ---------------------------------------------------------------------------
__global__ __launch_bounds__(256) void weights_prep(const float* __restrict__ Wg,
                                                    const float* __restrict__ Wb,
                                                    u16* __restrict__ wpre) {
    int layer = blockIdx.y;
    int idx = blockIdx.x * 256 + threadIdx.x;   // 0..8191
    int e = idx & 7, l = (idx >> 3) & 63, t = (idx >> 9) & 3, s = idx >> 11;
    int k = 32 * s + 8 * (l >> 4) + e;
    int n = 16 * t + (l & 15);
    float wv = (k < 64) ? Wg[layer * 4096 + k * 64 + n]
                        : Wb[layer * 4096 + (k - 64) * 64 + n];
    wpre[layer * 8192 + idx] = f2b(wv);
}

// ---------------------------------------------------------------------------
// SpMM v4 (R13, proven): 16-lane row-groups, dwordx2 gathers, 32 edges in
// flight per wave, no cross-lane reduce, col-sweep via persistent grid.
// ---------------------------------------------------------------------------
__global__ __launch_bounds__(256, 4) void spmm(const int* __restrict__ rs,
                                               const int* __restrict__ colS,
                                               const u16* __restrict__ valS,
                                               const u32* __restrict__ ego32,
                                               u32*       __restrict__ side32) {
    int tid = threadIdx.x;
    int w = tid >> 6, lane = tid & 63;
    int g = lane >> 4, d = lane & 15;
    const uint2* ego64 = (const uint2*)ego32;

    for (int row = blockIdx.x * 16 + w * 4 + g; row < NNODES; row += 32768) {
        int j0 = rs[row], j1 = rs[row + 1];
        float a0 = 0.f, a1 = 0.f, a2 = 0.f, a3 = 0.f;
        float b0 = 0.f, b1 = 0.f, b2 = 0.f, b3 = 0.f;
        int j = j0;
        for (; j + 8 <= j1; j += 8) {
            int   c[8]; float v[8]; uint2 gg[8];
            #pragma unroll
            for (int s = 0; s < 8; ++s) { c[s] = colS[j + s]; v[s] = us2f(valS[j + s]); }
            #pragma unroll
            for (int s = 0; s < 8; ++s) gg[s] = ego64[(size_t)c[s] * 16 + d];
            #pragma unroll
            for (int s = 0; s < 8; ++s) {
                if (s & 1) {
                    b0 = fmaf(v[s], __uint_as_float(gg[s].x << 16),          b0);
                    b1 = fmaf(v[s], __uint_as_float(gg[s].x & 0xFFFF0000u),  b1);
                    b2 = fmaf(v[s], __uint_as_float(gg[s].y << 16),          b2);
                    b3 = fmaf(v[s], __uint_as_float(gg[s].y & 0xFFFF0000u),  b3);
                } else {
                    a0 = fmaf(v[s], __uint_as_float(gg[s].x << 16),          a0);
                    a1 = fmaf(v[s], __uint_as_float(gg[s].x & 0xFFFF0000u),  a1);
                    a2 = fmaf(v[s], __uint_as_float(gg[s].y << 16),          a2);
                    a3 = fmaf(v[s], __uint_as_float(gg[s].y & 0xFFFF0000u),  a3);
                }
            }
        }
        for (; j < j1; ++j) {
            int cc = colS[j];
            float vv = us2f(valS[j]);
            uint2 gg = ego64[(size_t)cc * 16 + d];
            a0 = fmaf(vv, __uint_as_float(gg.x << 16),         a0);
            a1 = fmaf(vv, __uint_as_float(gg.x & 0xFFFF0000u), a1);
            a2 = fmaf(vv, __uint_as_float(gg.y << 16),         a2);
            a3 = fmaf(vv, __uint_as_float(gg.y & 0xFFFF0000u), a3);
        }
        a0 += b0; a1 += b1; a2 += b2; a3 += b3;
        uint2 o;
        o.x = (u32)f2b(a0) | ((u32)f2b(a1) << 16);
        o.y = (u32)f2b(a2) | ((u32)f2b(a3) << 16);
        ((uint2*)side32)[(size_t)row * 16 + d] = o;
    }
}

// ---------------------------------------------------------------------------
// Dense layer via MFMA + fused L2-normalize (R12, proven):
//   C = [side | ego*side] @ [Wg;Wb] + bias, leaky-relu
//   out col (layer+1) <- C/||C||; egoOut <- bf16(C)
// ---------------------------------------------------------------------------
__global__ __launch_bounds__(256) void dense_mfma(const u16* __restrict__ side,
                                                  float*     __restrict__ out,
                                                  const u16* __restrict__ egoIn,
                                                  u16*       __restrict__ egoOut,
                                                  const u16* __restrict__ wpre,
                                                  const float* __restrict__ bg,
                                                  const float* __restrict__ bb,
                                                  int layer) {
    __shared__ u16 bfr[8192];
    __shared__ float lbias[64];

    int tid = threadIdx.x;
    {
        const uint4* src = (const uint4*)(wpre + layer * 8192);
        uint4* dst = (uint4*)bfr;
        #pragma unroll
        for (int i = 0; i < 4; ++i) dst[tid + 256 * i] = src[tid + 256 * i];
    }
    if (tid < 64) lbias[tid] = bg[layer * 64 + tid] + bb[layer * 64 + tid];
    __syncthreads();

    int w = tid >> 6, lane = tid & 63;
    int g = lane >> 4, m = lane & 15;
    int rb = blockIdx.x * 64 + w * 16;
    int rowc = min(rb + m, NNODES - 1);

    bf16x8 sf0 = *(const bf16x8*)(side + (size_t)rowc * DIM + g * 8);
    bf16x8 sf1 = *(const bf16x8*)(side + (size_t)rowc * DIM + 32 + g * 8);
    bf16x8 ef0 = *(const bf16x8*)(egoIn + (size_t)rowc * DIM + g * 8);
    bf16x8 ef1 = *(const bf16x8*)(egoIn + (size_t)rowc * DIM + 32 + g * 8);
    bf16x8 pf0, pf1;
    #pragma unroll
    for (int e = 0; e < 8; ++e) {
        pf0[e] = (short)f2b(us2f((u16)ef0[e]) * us2f((u16)sf0[e]));
        pf1[e] = (short)f2b(us2f((u16)ef1[e]) * us2f((u16)sf1[e]));
    }

    const bf16x8* B = (const bf16x8*)bfr;
    f32x4 acc[4];
    #pragma unroll
    for (int t = 0; t < 4; ++t) {
        acc[t] = (f32x4){0.f, 0.f, 0.f, 0.f};
        acc[t] = __builtin_amdgcn_mfma_f32_16x16x32_bf16(sf0, B[(0 * 4 + t) * 64 + lane], acc[t], 0, 0, 0);
        acc[t] = __builtin_amdgcn_mfma_f32_16x16x32_bf16(sf1, B[(1 * 4 + t) * 64 + lane], acc[t], 0, 0, 0);
        acc[t] = __builtin_amdgcn_mfma_f32_16x16x32_bf16(pf0, B[(2 * 4 + t) * 64 + lane], acc[t], 0, 0, 0);
        acc[t] = __builtin_amdgcn_mfma_f32_16x16x32_bf16(pf1, B[(3 * 4 + t) * 64 + lane], acc[t], 0, 0, 0);
    }

    float vv[4][4], ss[4];
    #pragma unroll
    for (int r = 0; r < 4; ++r) {
        float sr = 0.f;
        #pragma unroll
        for (int t = 0; t < 4; ++t) {
            float v = acc[t][r] + lbias[16 * t + m];
            v = v >= 0.f ? v : 0.2f * v;
            vv[t][r] = v;
            sr += v * v;
        }
        ss[r] = sr;
    }
    #pragma unroll
    for (int off = 1; off < 16; off <<= 1) {
        #pragma unroll
        for (int r = 0; r < 4; ++r) ss[r] += __shfl_xor(ss[r], off, 64);
    }
    #pragma unroll
    for (int r = 0; r < 4; ++r) {
        int rw = rb + 4 * g + r;
        if (rw < NNODES) {
            float rn = 1.f / fmaxf(sqrtf(ss[r]), 1e-12f);
            #pragma unroll
            for (int t = 0; t < 4; ++t) {
                out[(size_t)rw * OSTRIDE + (layer + 1) * DIM + 16 * t + m] = vv[t][r] * rn;
                egoOut[(size_t)rw * DIM + 16 * t + m] = f2b(vv[t][r]);
            }
        }
    }
}

// ---------------------------------------------------------------------------
extern "C" void kernel_launch(void* const* d_in, const int* in_sizes, int n_in,
                              void* d_out, int out_size, void* d_ws, size_t ws_size,
                              hipStream_t stream) {
    const float* ue   = (const float*)d_in[0];
    const float* ie   = (const float*)d_in[1];
    const float* Wg   = (const float*)d_in[2];
    const float* bg   = (const float*)d_in[3];
    const float* Wb   = (const float*)d_in[4];
    const float* bb   = (const float*)d_in[5];
    const int*   rows = (const int*)d_in[6];
    const int*   cols = (const int*)d_in[7];
    const float* vals = (const float*)d_in[8];
    float* out = (float*)d_out;

    // ws layout (R11, proven), E = NEDGES:
    //  [0,8E) tmp int2 -> dead -> [0,4E) colS, [4E,5E) valS, [6E,10E) egoA
    //  [8E,12E) colT u32, [12E,14E) valT u16 (dead after to_csr)
    //  [10E,14E) egoB, [14E,18E) side, [18E..) rs/meta/wpre
    char* base = (char*)d_ws;
    const size_t E = NEDGES;
    int2* tmp  = (int2*)base;
    u32*  colT = (u32*)(base + 8 * E);
    u16*  valT = (u16*)(base + 12 * E);
    int*  colS = (int*)base;
    u16*  valS = (u16*)(base + 4 * E);
    u16*  egoA = (u16*)(base + 6 * E);
    u16*  egoB = (u16*)(base + 10 * E);
    u16*  side = (u16*)(base + 14 * E);
    int*  rs     = (int*)(base + 18 * E);
    int*  bcount  = rs + NNODES + 1;
    int*  bbase   = bcount + NBUCK;
    int*  bcursor = bbase + NBUCK + 1;
    u16*  wpre    = (u16*)(bcursor + NBUCK);

    hipMemsetAsync(bcount, 0, NBUCK * sizeof(int), stream);
    bucket_count<<<NPBLK_C, 256, 0, stream>>>(rows, bcount);
    bucket_scan<<<1, 512, 0, stream>>>(bcount, bbase, bcursor);
    bucket_place<<<NPBLK_P, 256, 0, stream>>>(rows, cols, vals, bcursor, tmp);
    bucket_colsort<<<NBUCK, 256, 0, stream>>>(bbase, tmp, colT, valT);
    bucket_to_csr<<<NBUCK, 256, 0, stream>>>(bbase, colT, valT, rs, colS, valS);

    weights_prep<<<dim3(32, 3), 256, 0, stream>>>(Wg, Wb, wpre);

    // init_ego AFTER to_csr: egoA overlaps dead tmp/colT regions
    init_ego<<<(NNODES * 16 + 255) / 256, 256, 0, stream>>>(ue, ie, out, (u32*)egoA);

    u16* ei = egoA; u16* eo = egoB;
    for (int l = 0; l < 3; ++l) {
        spmm<<<2048, 256, 0, stream>>>(rs, colS, valS, (const u32*)ei, (u32*)side);
        dense_mfma<<<(NNODES + 63) / 64, 256, 0, stream>>>(side, out, ei, eo,
                                                           wpre, bg, bb, l);
        u16* t = ei; ei = eo; eo = t;
    }
}

// Round 15
// 423.045 us; speedup vs baseline: 1.0911x; 1.0911x over previous
//
#include <hip/hip_runtime.h>
#include <hip/hip_bf16.h>

#define NUSERS  50000
#define NNODES  100000
#define NEDGES  3200000
#define DIM     64
#define OSTRIDE 256   // output row stride: (3+1)*64
#define NBUCK   391   // ceil(NNODES/256): 256-row buckets
#define EPB     8192  // edges per block in bucketing kernels (391 blocks; 2048 regressed twice)
#define NPBLK   391
#define NCOLB   391   // col>>8 bins
#define LSTR2   72    // u16 stride of LDS side tile: 144B/row, 16B-aligned, 2-way banks

typedef unsigned short u16;
typedef unsigned int u32;
typedef __attribute__((ext_vector_type(8))) short bf16x8;
typedef __attribute__((ext_vector_type(4))) float f32x4;

__device__ __forceinline__ float us2f(u16 u) {
    return __uint_as_float((u32)u << 16);
}
__device__ __forceinline__ u16 f2b(float f) {           // f32 -> bf16 RNE bits
    u32 u = __float_as_uint(f);
    return (u16)((u + 0x7fffu + ((u >> 16) & 1u)) >> 16);
}

// ---------------------------------------------------------------------------
// out[:, 0:64] = concat(ue, ie) (fp32); ego[N][64] bf16
// ---------------------------------------------------------------------------
__global__ __launch_bounds__(256) void init_ego(const float* __restrict__ ue,
                                                const float* __restrict__ ie,
                                                float* __restrict__ out,
                                                u32*   __restrict__ ego32) {
    int gid = blockIdx.x * 256 + threadIdx.x;
    if (gid >= NNODES * 16) return;
    int node = gid >> 4, c = gid & 15;
    float4 v = (node < NUSERS)
        ? ((const float4*)ue)[node * 16 + c]
        : ((const float4*)ie)[(size_t)(node - NUSERS) * 16 + c];
    ((float4*)(out + (size_t)node * OSTRIDE))[c] = v;
    u32* d = ego32 + (size_t)node * 32 + 2 * c;
    d[0] = (u32)f2b(v.x) | ((u32)f2b(v.y) << 16);
    d[1] = (u32)f2b(v.z) | ((u32)f2b(v.w) << 16);
}

// ---------------------------------------------------------------------------
// Pass 1: counting sort by row>>8 into 256-row buckets (R11-proven, 391 blk)
// ---------------------------------------------------------------------------
__global__ __launch_bounds__(256) void bucket_count(const int* __restrict__ rows,
                                                    int* __restrict__ bcount) {
    __shared__ int lh[NBUCK];
    int tid = threadIdx.x;
    for (int i = tid; i < NBUCK; i += 256) lh[i] = 0;
    __syncthreads();
    int e0 = blockIdx.x * EPB, e1 = min(e0 + EPB, NEDGES);
    for (int e = e0 + tid; e < e1; e += 256)
        atomicAdd(&lh[rows[e] >> 8], 1);
    __syncthreads();
    for (int i = tid; i < NBUCK; i += 256)
        if (lh[i]) atomicAdd(&bcount[i], lh[i]);
}

__global__ __launch_bounds__(512) void bucket_scan(const int* __restrict__ bcount,
                                                   int* __restrict__ bbase,
                                                   int* __restrict__ bcursor) {
    __shared__ int sc[512];
    int tid = threadIdx.x;
    int v = (tid < NBUCK) ? bcount[tid] : 0;
    sc[tid] = v;
    __syncthreads();
    for (int off = 1; off < 512; off <<= 1) {
        int t = (tid >= off) ? sc[tid - off] : 0;
        __syncthreads();
        sc[tid] += t;
        __syncthreads();
    }
    if (tid < NBUCK) {
        int excl = sc[tid] - v;
        bbase[tid] = excl;
        bcursor[tid] = excl;
    }
    if (tid == 0) bbase[NBUCK] = NEDGES;
}

__global__ __launch_bounds__(256) void bucket_place(const int*   __restrict__ rows,
                                                    const int*   __restrict__ cols,
                                                    const float* __restrict__ vals,
                                                    int*  __restrict__ bcursor,
                                                    int2* __restrict__ tmp) {
    __shared__ int lh[NBUCK];
    int tid = threadIdx.x;
    for (int i = tid; i < NBUCK; i += 256) lh[i] = 0;
    __syncthreads();
    int e0 = blockIdx.x * EPB, e1 = min(e0 + EPB, NEDGES);
    for (int e = e0 + tid; e < e1; e += 256)
        atomicAdd(&lh[rows[e] >> 8], 1);
    __syncthreads();
    for (int i = tid; i < NBUCK; i += 256) {
        int c = lh[i];
        lh[i] = c ? atomicAdd(&bcursor[i], c) : 0;
    }
    __syncthreads();
    for (int e = e0 + tid; e < e1; e += 256) {
        int r = rows[e];
        int p = atomicAdd(&lh[r >> 8], 1);
        tmp[p] = make_int2(((r & 255) << 20) | cols[e], (int)f2b(vals[e]));
    }
}

// ---------------------------------------------------------------------------
// Pass 2: within each 256-row bucket, order edges by col>>8 bin.
// ---------------------------------------------------------------------------
__global__ __launch_bounds__(256) void bucket_colsort(const int*  __restrict__ bbase,
                                                      const int2* __restrict__ tmp,
                                                      u32* __restrict__ colT,
                                                      u16* __restrict__ valT) {
    __shared__ int cnt[NCOLB];
    __shared__ int tsum[256];
    int b = blockIdx.x, tid = threadIdx.x;
    int j0 = bbase[b], j1 = bbase[b + 1];
    for (int i = tid; i < NCOLB; i += 256) cnt[i] = 0;
    __syncthreads();
    for (int j = j0 + tid; j < j1; j += 256)
        atomicAdd(&cnt[(tmp[j].x & 0xFFFFF) >> 8], 1);
    __syncthreads();
    int i0 = 2 * tid, i1 = 2 * tid + 1;
    int c0 = (i0 < NCOLB) ? cnt[i0] : 0;
    int c1 = (i1 < NCOLB) ? cnt[i1] : 0;
    int tot = c0 + c1;
    tsum[tid] = tot;
    __syncthreads();
    for (int off = 1; off < 256; off <<= 1) {
        int t = (tid >= off) ? tsum[tid - off] : 0;
        __syncthreads();
        tsum[tid] += t;
        __syncthreads();
    }
    int run = j0 + tsum[tid] - tot;
    if (i0 < NCOLB) { cnt[i0] = run; run += c0; }
    if (i1 < NCOLB) cnt[i1] = run;
    __syncthreads();
    for (int j = j0 + tid; j < j1; j += 256) {
        int2 t2 = tmp[j];
        int q = atomicAdd(&cnt[(t2.x & 0xFFFFF) >> 8], 1);
        colT[q] = (u32)t2.x;
        valT[q] = (u16)t2.y;
    }
}

// ---------------------------------------------------------------------------
// Pass 3: bin-ordered stream -> row-major CSR (per-row edges ~col-sorted)
// ---------------------------------------------------------------------------
__global__ __launch_bounds__(256) void bucket_to_csr(const int* __restrict__ bbase,
                                                     const u32* __restrict__ colT,
                                                     const u16* __restrict__ valT,
                                                     int* __restrict__ rs,
                                                     int* __restrict__ colS,
                                                     u16* __restrict__ valS) {
    __shared__ int rcnt[256];
    __shared__ int cur[256];
    int b = blockIdx.x, tid = threadIdx.x;
    int j0 = bbase[b], j1 = bbase[b + 1];
    rcnt[tid] = 0;
    __syncthreads();
    for (int j = j0 + tid; j < j1; j += 256)
        atomicAdd(&rcnt[colT[j] >> 20], 1);
    __syncthreads();
    int own = rcnt[tid];
    for (int off = 1; off < 256; off <<= 1) {
        int t = (tid >= off) ? rcnt[tid - off] : 0;
        __syncthreads();
        rcnt[tid] += t;
        __syncthreads();
    }
    int start = j0 + rcnt[tid] - own;
    int row = b * 256 + tid;
    if (row < NNODES) rs[row] = start;
    if (b == 0 && tid == 0) rs[NNODES] = NEDGES;
    cur[tid] = start;
    __syncthreads();
    for (int j = j0 + tid; j < j1; j += 256) {
        u32 cx = colT[j];
        int p = atomicAdd(&cur[cx >> 20], 1);
        colS[p] = cx & 0xFFFFF;
        valS[p] = valT[j];
    }
}

// ---------------------------------------------------------------------------
// Pre-convert weights to fragment-ordered bf16 (R7, proven)
// ---------------------------------------------------------------------------
__global__ __launch_bounds__(256) void weights_prep(const float* __restrict__ Wg,
                                                    const float* __restrict__ Wb,
                                                    u16* __restrict__ wpre) {
    int layer = blockIdx.y;
    int idx = blockIdx.x * 256 + threadIdx.x;   // 0..8191
    int e = idx & 7, l = (idx >> 3) & 63, t = (idx >> 9) & 3, s = idx >> 11;
    int k = 32 * s + 8 * (l >> 4) + e;
    int n = 16 * t + (l & 15);
    float wv = (k < 64) ? Wg[layer * 4096 + k * 64 + n]
                        : Wb[layer * 4096 + (k - 64) * 64 + n];
    wpre[layer * 8192 + idx] = f2b(wv);
}

// ---------------------------------------------------------------------------
// Fused layer (R15): one block per 64 consecutive rows.
//  Phase A: R13-proven gather SpMM (16-lane row-groups, dwordx2, 32 edges in
//           flight/wave), side tile -> LDS bf16 (stride 72 u16: 16B-aligned,
//           2-way banks = free).
//  Phase B: R12-proven MFMA dense + bias + leaky-relu + fused L2-normalize;
//           side fragments read from LDS. Kills global side buffer entirely.
// ---------------------------------------------------------------------------
__global__ __launch_bounds__(256, 4) void fused_layer(const int* __restrict__ rs,
                                                      const int* __restrict__ colS,
                                                      const u16* __restrict__ valS,
                                                      const u16* __restrict__ egoIn,
                                                      u16*       __restrict__ egoOut,
                                                      float*     __restrict__ out,
                                                      const u16* __restrict__ wpre,
                                                      const float* __restrict__ bg,
                                                      const float* __restrict__ bb,
                                                      int layer) {
    __shared__ u16 bfr[8192];
    __shared__ float lbias[64];
    __shared__ u16 sideL[64 * LSTR2];   // 9 KB

    int tid = threadIdx.x;
    {
        const uint4* src = (const uint4*)(wpre + layer * 8192);
        uint4* dst = (uint4*)bfr;
        #pragma unroll
        for (int i = 0; i < 4; ++i) dst[tid + 256 * i] = src[tid + 256 * i];
    }
    if (tid < 64) lbias[tid] = bg[layer * 64 + tid] + bb[layer * 64 + tid];

    int w = tid >> 6, lane = tid & 63;
    int grp = lane >> 4, d = lane & 15;
    const uint2* ego64 = (const uint2*)egoIn;
    int rb = blockIdx.x * 64;

    // ---- Phase A: gather SpMM into LDS side tile ----
    #pragma unroll
    for (int sub = 0; sub < 4; ++sub) {
        int lr = sub * 16 + w * 4 + grp;
        int row = rb + lr;
        if (row < NNODES) {
            int j0 = rs[row], j1 = rs[row + 1];
            float a0 = 0.f, a1 = 0.f, a2 = 0.f, a3 = 0.f;
            float b0 = 0.f, b1 = 0.f, b2 = 0.f, b3 = 0.f;
            int j = j0;
            for (; j + 8 <= j1; j += 8) {
                int   c[8]; float v[8]; uint2 gg[8];
                #pragma unroll
                for (int s = 0; s < 8; ++s) { c[s] = colS[j + s]; v[s] = us2f(valS[j + s]); }
                #pragma unroll
                for (int s = 0; s < 8; ++s) gg[s] = ego64[(size_t)c[s] * 16 + d];
                #pragma unroll
                for (int s = 0; s < 8; ++s) {
                    if (s & 1) {
                        b0 = fmaf(v[s], __uint_as_float(gg[s].x << 16),         b0);
                        b1 = fmaf(v[s], __uint_as_float(gg[s].x & 0xFFFF0000u), b1);
                        b2 = fmaf(v[s], __uint_as_float(gg[s].y << 16),         b2);
                        b3 = fmaf(v[s], __uint_as_float(gg[s].y & 0xFFFF0000u), b3);
                    } else {
                        a0 = fmaf(v[s], __uint_as_float(gg[s].x << 16),         a0);
                        a1 = fmaf(v[s], __uint_as_float(gg[s].x & 0xFFFF0000u), a1);
                        a2 = fmaf(v[s], __uint_as_float(gg[s].y << 16),         a2);
                        a3 = fmaf(v[s], __uint_as_float(gg[s].y & 0xFFFF0000u), a3);
                    }
                }
            }
            for (; j < j1; ++j) {
                int cc = colS[j];
                float vv = us2f(valS[j]);
                uint2 gg = ego64[(size_t)cc * 16 + d];
                a0 = fmaf(vv, __uint_as_float(gg.x << 16),         a0);
                a1 = fmaf(vv, __uint_as_float(gg.x & 0xFFFF0000u), a1);
                a2 = fmaf(vv, __uint_as_float(gg.y << 16),         a2);
                a3 = fmaf(vv, __uint_as_float(gg.y & 0xFFFF0000u), a3);
            }
            a0 += b0; a1 += b1; a2 += b2; a3 += b3;
            uint2 o;
            o.x = (u32)f2b(a0) | ((u32)f2b(a1) << 16);
            o.y = (u32)f2b(a2) | ((u32)f2b(a3) << 16);
            *(uint2*)&sideL[lr * LSTR2 + 4 * d] = o;   // dims 4d..4d+3
        }
    }
    __syncthreads();

    // ---- Phase B: MFMA dense + bias + leaky-relu + fused normalize ----
    int g2 = lane >> 4, m = lane & 15;
    int lrB = w * 16 + m;
    int rowc = min(rb + lrB, NNODES - 1);

    bf16x8 sf0 = *(const bf16x8*)&sideL[lrB * LSTR2 + g2 * 8];
    bf16x8 sf1 = *(const bf16x8*)&sideL[lrB * LSTR2 + 32 + g2 * 8];
    bf16x8 ef0 = *(const bf16x8*)(egoIn + (size_t)rowc * DIM + g2 * 8);
    bf16x8 ef1 = *(const bf16x8*)(egoIn + (size_t)rowc * DIM + 32 + g2 * 8);
    bf16x8 pf0, pf1;
    #pragma unroll
    for (int e = 0; e < 8; ++e) {
        pf0[e] = (short)f2b(us2f((u16)ef0[e]) * us2f((u16)sf0[e]));
        pf1[e] = (short)f2b(us2f((u16)ef1[e]) * us2f((u16)sf1[e]));
    }

    const bf16x8* B = (const bf16x8*)bfr;
    f32x4 acc[4];
    #pragma unroll
    for (int t = 0; t < 4; ++t) {
        acc[t] = (f32x4){0.f, 0.f, 0.f, 0.f};
        acc[t] = __builtin_amdgcn_mfma_f32_16x16x32_bf16(sf0, B[(0 * 4 + t) * 64 + lane], acc[t], 0, 0, 0);
        acc[t] = __builtin_amdgcn_mfma_f32_16x16x32_bf16(sf1, B[(1 * 4 + t) * 64 + lane], acc[t], 0, 0, 0);
        acc[t] = __builtin_amdgcn_mfma_f32_16x16x32_bf16(pf0, B[(2 * 4 + t) * 64 + lane], acc[t], 0, 0, 0);
        acc[t] = __builtin_amdgcn_mfma_f32_16x16x32_bf16(pf1, B[(3 * 4 + t) * 64 + lane], acc[t], 0, 0, 0);
    }

    float vv[4][4], ss[4];
    #pragma unroll
    for (int r = 0; r < 4; ++r) {
        float sr = 0.f;
        #pragma unroll
        for (int t = 0; t < 4; ++t) {
            float v = acc[t][r] + lbias[16 * t + m];
            v = v >= 0.f ? v : 0.2f * v;
            vv[t][r] = v;
            sr += v * v;
        }
        ss[r] = sr;
    }
    #pragma unroll
    for (int off = 1; off < 16; off <<= 1) {
        #pragma unroll
        for (int r = 0; r < 4; ++r) ss[r] += __shfl_xor(ss[r], off, 64);
    }
    #pragma unroll
    for (int r = 0; r < 4; ++r) {
        int rw = rb + w * 16 + 4 * g2 + r;
        if (rw < NNODES) {
            float rn = 1.f / fmaxf(sqrtf(ss[r]), 1e-12f);
            #pragma unroll
            for (int t = 0; t < 4; ++t) {
                out[(size_t)rw * OSTRIDE + (layer + 1) * DIM + 16 * t + m] = vv[t][r] * rn;
                egoOut[(size_t)rw * DIM + 16 * t + m] = f2b(vv[t][r]);
            }
        }
    }
}

// ---------------------------------------------------------------------------
extern "C" void kernel_launch(void* const* d_in, const int* in_sizes, int n_in,
                              void* d_out, int out_size, void* d_ws, size_t ws_size,
                              hipStream_t stream) {
    const float* ue   = (const float*)d_in[0];
    const float* ie   = (const float*)d_in[1];
    const float* Wg   = (const float*)d_in[2];
    const float* bg   = (const float*)d_in[3];
    const float* Wb   = (const float*)d_in[4];
    const float* bb   = (const float*)d_in[5];
    const int*   rows = (const int*)d_in[6];
    const int*   cols = (const int*)d_in[7];
    const float* vals = (const float*)d_in[8];
    float* out = (float*)d_out;

    // ws layout (R11, proven), E = NEDGES:
    //  [0,8E) tmp int2 -> dead -> [0,4E) colS, [4E,5E) valS, [6E,10E) egoA
    //  [8E,12E) colT u32, [12E,14E) valT u16 (dead after to_csr)
    //  [10E,14E) egoB, [18E..) rs/meta/wpre
    char* base = (char*)d_ws;
    const size_t E = NEDGES;
    int2* tmp  = (int2*)base;
    u32*  colT = (u32*)(base + 8 * E);
    u16*  valT = (u16*)(base + 12 * E);
    int*  colS = (int*)base;
    u16*  valS = (u16*)(base + 4 * E);
    u16*  egoA = (u16*)(base + 6 * E);
    u16*  egoB = (u16*)(base + 10 * E);
    int*  rs     = (int*)(base + 18 * E);
    int*  bcount  = rs + NNODES + 1;
    int*  bbase   = bcount + NBUCK;
    int*  bcursor = bbase + NBUCK + 1;
    u16*  wpre    = (u16*)(bcursor + NBUCK);

    hipMemsetAsync(bcount, 0, NBUCK * sizeof(int), stream);
    bucket_count<<<NPBLK, 256, 0, stream>>>(rows, bcount);
    bucket_scan<<<1, 512, 0, stream>>>(bcount, bbase, bcursor);
    bucket_place<<<NPBLK, 256, 0, stream>>>(rows, cols, vals, bcursor, tmp);
    bucket_colsort<<<NBUCK, 256, 0, stream>>>(bbase, tmp, colT, valT);
    bucket_to_csr<<<NBUCK, 256, 0, stream>>>(bbase, colT, valT, rs, colS, valS);

    weights_prep<<<dim3(32, 3), 256, 0, stream>>>(Wg, Wb, wpre);

    // init_ego AFTER to_csr: egoA overlaps dead tmp/colT regions
    init_ego<<<(NNODES * 16 + 255) / 256, 256, 0, stream>>>(ue, ie, out, (u32*)egoA);

    u16* ei = egoA; u16* eo = egoB;
    for (int l = 0; l < 3; ++l) {
        fused_layer<<<(NNODES + 63) / 64, 256, 0, stream>>>(rs, colS, valS, ei, eo,
                                                            out, wpre, bg, bb, l);
        u16* t = ei; ei = eo; eo = t;
    }
}

// Round 17
// 381.449 us; speedup vs baseline: 1.2101x; 1.1090x over previous
//
#include <hip/hip_runtime.h>
#include <hip/hip_bf16.h>

#define NUSERS  50000
#define NNODES  100000
#define NEDGES  3200000
#define DIM     64
#define OSTRIDE 256   // output row stride: (3+1)*64
#define NBUCK   391   // ceil(NNODES/256): 256-row buckets
#define EPB     8192  // edges per block in bucketing kernels
#define NPBLK   391
#define NCOLB   391   // col>>8 bins
#define BCAP    8704  // max edges per 256-row bucket (mean 8192, +5.7 sigma)
#define LSTR2   72    // u16 stride of LDS side tile: 144B/row, 16B-aligned

typedef unsigned short u16;
typedef unsigned int u32;
typedef __attribute__((ext_vector_type(8))) short bf16x8;
typedef __attribute__((ext_vector_type(4))) float f32x4;

__device__ __forceinline__ float us2f(u16 u) {
    return __uint_as_float((u32)u << 16);
}
__device__ __forceinline__ u16 f2b(float f) {           // f32 -> bf16 RNE bits
    u32 u = __float_as_uint(f);
    return (u16)((u + 0x7fffu + ((u >> 16) & 1u)) >> 16);
}

// ---------------------------------------------------------------------------
// out[:, 0:64] = concat(ue, ie) (fp32); ego[N][64] bf16
// ---------------------------------------------------------------------------
__global__ __launch_bounds__(256) void init_ego(const float* __restrict__ ue,
                                                const float* __restrict__ ie,
                                                float* __restrict__ out,
                                                u32*   __restrict__ ego32) {
    int gid = blockIdx.x * 256 + threadIdx.x;
    if (gid >= NNODES * 16) return;
    int node = gid >> 4, c = gid & 15;
    float4 v = (node < NUSERS)
        ? ((const float4*)ue)[node * 16 + c]
        : ((const float4*)ie)[(size_t)(node - NUSERS) * 16 + c];
    ((float4*)(out + (size_t)node * OSTRIDE))[c] = v;
    u32* d = ego32 + (size_t)node * 32 + 2 * c;
    d[0] = (u32)f2b(v.x) | ((u32)f2b(v.y) << 16);
    d[1] = (u32)f2b(v.z) | ((u32)f2b(v.w) << 16);
}

// ---------------------------------------------------------------------------
// Pass 1: counting sort by row>>8 into 256-row buckets (R11-proven, 391 blk)
// ---------------------------------------------------------------------------
__global__ __launch_bounds__(256) void bucket_count(const int* __restrict__ rows,
                                                    int* __restrict__ bcount) {
    __shared__ int lh[NBUCK];
    int tid = threadIdx.x;
    for (int i = tid; i < NBUCK; i += 256) lh[i] = 0;
    __syncthreads();
    int e0 = blockIdx.x * EPB, e1 = min(e0 + EPB, NEDGES);
    for (int e = e0 + tid; e < e1; e += 256)
        atomicAdd(&lh[rows[e] >> 8], 1);
    __syncthreads();
    for (int i = tid; i < NBUCK; i += 256)
        if (lh[i]) atomicAdd(&bcount[i], lh[i]);
}

__global__ __launch_bounds__(512) void bucket_scan(const int* __restrict__ bcount,
                                                   int* __restrict__ bbase,
                                                   int* __restrict__ bcursor) {
    __shared__ int sc[512];
    int tid = threadIdx.x;
    int v = (tid < NBUCK) ? bcount[tid] : 0;
    sc[tid] = v;
    __syncthreads();
    for (int off = 1; off < 512; off <<= 1) {
        int t = (tid >= off) ? sc[tid - off] : 0;
        __syncthreads();
        sc[tid] += t;
        __syncthreads();
    }
    if (tid < NBUCK) {
        int excl = sc[tid] - v;
        bbase[tid] = excl;
        bcursor[tid] = excl;
    }
    if (tid == 0) bbase[NBUCK] = NEDGES;
}

__global__ __launch_bounds__(256) void bucket_place(const int*   __restrict__ rows,
                                                    const int*   __restrict__ cols,
                                                    const float* __restrict__ vals,
                                                    int*  __restrict__ bcursor,
                                                    int2* __restrict__ tmp) {
    __shared__ int lh[NBUCK];
    int tid = threadIdx.x;
    for (int i = tid; i < NBUCK; i += 256) lh[i] = 0;
    __syncthreads();
    int e0 = blockIdx.x * EPB, e1 = min(e0 + EPB, NEDGES);
    for (int e = e0 + tid; e < e1; e += 256)
        atomicAdd(&lh[rows[e] >> 8], 1);
    __syncthreads();
    for (int i = tid; i < NBUCK; i += 256) {
        int c = lh[i];
        lh[i] = c ? atomicAdd(&bcursor[i], c) : 0;
    }
    __syncthreads();
    for (int e = e0 + tid; e < e1; e += 256) {
        int r = rows[e];
        int p = atomicAdd(&lh[r >> 8], 1);
        tmp[p] = make_int2(((r & 255) << 20) | cols[e], (int)f2b(vals[e]));
    }
}

// ---------------------------------------------------------------------------
// Pass 2+3 merged: per 256-row bucket, stage edges in LDS ordered by col>>8
// bin, re-histogram by row, emit final CSR. Output colS/valS is in a region
// DISJOINT from tmp (R16 aliased them -> race -> crash; fixed here).
// ---------------------------------------------------------------------------
__global__ __launch_bounds__(256) void bucket_build(const int*  __restrict__ bbase,
                                                    const int2* __restrict__ tmp,
                                                    int* __restrict__ rs,
                                                    int* __restrict__ colS,
                                                    u16* __restrict__ valS) {
    __shared__ int cnt[NCOLB];
    __shared__ int tsum[256];
    __shared__ int rcnt[256];
    __shared__ int cur[256];
    __shared__ u32 colL[BCAP];   // 34 KB
    __shared__ u16 valL[BCAP];   // 17 KB

    int b = blockIdx.x, tid = threadIdx.x;
    int j0 = bbase[b], j1 = bbase[b + 1];
    int n = j1 - j0;

    for (int i = tid; i < NCOLB; i += 256) cnt[i] = 0;
    rcnt[tid] = 0;
    __syncthreads();
    for (int j = j0 + tid; j < j1; j += 256)
        atomicAdd(&cnt[(tmp[j].x & 0xFFFFF) >> 8], 1);
    __syncthreads();
    int i0 = 2 * tid, i1 = i0 + 1;
    int c0 = (i0 < NCOLB) ? cnt[i0] : 0;
    int c1 = (i1 < NCOLB) ? cnt[i1] : 0;
    int tot = c0 + c1;
    tsum[tid] = tot;
    __syncthreads();
    for (int off = 1; off < 256; off <<= 1) {
        int t = (tid >= off) ? tsum[tid - off] : 0;
        __syncthreads();
        tsum[tid] += t;
        __syncthreads();
    }
    int run = tsum[tid] - tot;
    if (i0 < NCOLB) { cnt[i0] = run; run += c0; }
    if (i1 < NCOLB) cnt[i1] = run;
    __syncthreads();
    for (int j = j0 + tid; j < j1; j += 256) {
        int2 t2 = tmp[j];
        int q = atomicAdd(&cnt[(t2.x & 0xFFFFF) >> 8], 1);
        if (q < BCAP) { colL[q] = (u32)t2.x; valL[q] = (u16)t2.y; }
        atomicAdd(&rcnt[((u32)t2.x) >> 20], 1);
    }
    __syncthreads();
    int own = rcnt[tid];
    for (int off = 1; off < 256; off <<= 1) {
        int t = (tid >= off) ? rcnt[tid - off] : 0;
        __syncthreads();
        rcnt[tid] += t;
        __syncthreads();
    }
    int start = rcnt[tid] - own;
    int row = b * 256 + tid;
    if (row < NNODES) rs[row] = j0 + start;
    if (b == 0 && tid == 0) rs[NNODES] = NEDGES;
    cur[tid] = start;
    __syncthreads();
    for (int i = tid; i < n && i < BCAP; i += 256) {
        u32 cx = colL[i];
        int p = j0 + atomicAdd(&cur[cx >> 20], 1);
        colS[p] = cx & 0xFFFFF;
        valS[p] = valL[i];
    }
}

// ---------------------------------------------------------------------------
// Pre-convert weights to fragment-ordered bf16 (R7, proven)
// ---------------------------------------------------------------------------
__global__ __launch_bounds__(256) void weights_prep(const float* __restrict__ Wg,
                                                    const float* __restrict__ Wb,
                                                    u16* __restrict__ wpre) {
    int layer = blockIdx.y;
    int idx = blockIdx.x * 256 + threadIdx.x;   // 0..8191
    int e = idx & 7, l = (idx >> 3) & 63, t = (idx >> 9) & 3, s = idx >> 11;
    int k = 32 * s + 8 * (l >> 4) + e;
    int n = 16 * t + (l & 15);
    float wv = (k < 64) ? Wg[layer * 4096 + k * 64 + n]
                        : Wb[layer * 4096 + (k - 64) * 64 + n];
    wpre[layer * 8192 + idx] = f2b(wv);
}

// ---------------------------------------------------------------------------
// Fused layer (R15 body + launch_bounds(256,6) -> 6 blocks/CU).
// Phase A: gather SpMM into LDS side tile. Phase B: MFMA dense + bias +
// leaky-relu + fused L2-normalize.
// ---------------------------------------------------------------------------
__global__ __launch_bounds__(256, 6) void fused_layer(const int* __restrict__ rs,
                                                      const int* __restrict__ colS,
                                                      const u16* __restrict__ valS,
                                                      const u16* __restrict__ egoIn,
                                                      u16*       __restrict__ egoOut,
                                                      float*     __restrict__ out,
                                                      const u16* __restrict__ wpre,
                                                      const float* __restrict__ bg,
                                                      const float* __restrict__ bb,
                                                      int layer) {
    __shared__ u16 bfr[8192];
    __shared__ float lbias[64];
    __shared__ u16 sideL[64 * LSTR2];   // 9 KB

    int tid = threadIdx.x;
    {
        const uint4* src = (const uint4*)(wpre + layer * 8192);
        uint4* dst = (uint4*)bfr;
        #pragma unroll
        for (int i = 0; i < 4; ++i) dst[tid + 256 * i] = src[tid + 256 * i];
    }
    if (tid < 64) lbias[tid] = bg[layer * 64 + tid] + bb[layer * 64 + tid];

    int w = tid >> 6, lane = tid & 63;
    int grp = lane >> 4, d = lane & 15;
    const uint2* ego64 = (const uint2*)egoIn;
    int rb = blockIdx.x * 64;

    // ---- Phase A: gather SpMM into LDS side tile ----
    #pragma unroll
    for (int sub = 0; sub < 4; ++sub) {
        int lr = sub * 16 + w * 4 + grp;
        int row = rb + lr;
        if (row < NNODES) {
            int j0 = rs[row], j1 = rs[row + 1];
            float a0 = 0.f, a1 = 0.f, a2 = 0.f, a3 = 0.f;
            float b0 = 0.f, b1 = 0.f, b2 = 0.f, b3 = 0.f;
            int j = j0;
            for (; j + 8 <= j1; j += 8) {
                int   c[8]; float v[8]; uint2 gg[8];
                #pragma unroll
                for (int s = 0; s < 8; ++s) { c[s] = colS[j + s]; v[s] = us2f(valS[j + s]); }
                #pragma unroll
                for (int s = 0; s < 8; ++s) gg[s] = ego64[(size_t)c[s] * 16 + d];
                #pragma unroll
                for (int s = 0; s < 8; ++s) {
                    if (s & 1) {
                        b0 = fmaf(v[s], __uint_as_float(gg[s].x << 16),         b0);
                        b1 = fmaf(v[s], __uint_as_float(gg[s].x & 0xFFFF0000u), b1);
                        b2 = fmaf(v[s], __uint_as_float(gg[s].y << 16),         b2);
                        b3 = fmaf(v[s], __uint_as_float(gg[s].y & 0xFFFF0000u), b3);
                    } else {
                        a0 = fmaf(v[s], __uint_as_float(gg[s].x << 16),         a0);
                        a1 = fmaf(v[s], __uint_as_float(gg[s].x & 0xFFFF0000u), a1);
                        a2 = fmaf(v[s], __uint_as_float(gg[s].y << 16),         a2);
                        a3 = fmaf(v[s], __uint_as_float(gg[s].y & 0xFFFF0000u), a3);
                    }
                }
            }
            for (; j < j1; ++j) {
                int cc = colS[j];
                float vv = us2f(valS[j]);
                uint2 gg = ego64[(size_t)cc * 16 + d];
                a0 = fmaf(vv, __uint_as_float(gg.x << 16),         a0);
                a1 = fmaf(vv, __uint_as_float(gg.x & 0xFFFF0000u), a1);
                a2 = fmaf(vv, __uint_as_float(gg.y << 16),         a2);
                a3 = fmaf(vv, __uint_as_float(gg.y & 0xFFFF0000u), a3);
            }
            a0 += b0; a1 += b1; a2 += b2; a3 += b3;
            uint2 o;
            o.x = (u32)f2b(a0) | ((u32)f2b(a1) << 16);
            o.y = (u32)f2b(a2) | ((u32)f2b(a3) << 16);
            *(uint2*)&sideL[lr * LSTR2 + 4 * d] = o;   // dims 4d..4d+3
        }
    }
    __syncthreads();

    // ---- Phase B: MFMA dense + bias + leaky-relu + fused normalize ----
    int g2 = lane >> 4, m = lane & 15;
    int lrB = w * 16 + m;
    int rowc = min(rb + lrB, NNODES - 1);

    bf16x8 sf0 = *(const bf16x8*)&sideL[lrB * LSTR2 + g2 * 8];
    bf16x8 sf1 = *(const bf16x8*)&sideL[lrB * LSTR2 + 32 + g2 * 8];
    bf16x8 ef0 = *(const bf16x8*)(egoIn + (size_t)rowc * DIM + g2 * 8);
    bf16x8 ef1 = *(const bf16x8*)(egoIn + (size_t)rowc * DIM + 32 + g2 * 8);
    bf16x8 pf0, pf1;
    #pragma unroll
    for (int e = 0; e < 8; ++e) {
        pf0[e] = (short)f2b(us2f((u16)ef0[e]) * us2f((u16)sf0[e]));
        pf1[e] = (short)f2b(us2f((u16)ef1[e]) * us2f((u16)sf1[e]));
    }

    const bf16x8* B = (const bf16x8*)bfr;
    f32x4 acc[4];
    #pragma unroll
    for (int t = 0; t < 4; ++t) {
        acc[t] = (f32x4){0.f, 0.f, 0.f, 0.f};
        acc[t] = __builtin_amdgcn_mfma_f32_16x16x32_bf16(sf0, B[(0 * 4 + t) * 64 + lane], acc[t], 0, 0, 0);
        acc[t] = __builtin_amdgcn_mfma_f32_16x16x32_bf16(sf1, B[(1 * 4 + t) * 64 + lane], acc[t], 0, 0, 0);
        acc[t] = __builtin_amdgcn_mfma_f32_16x16x32_bf16(pf0, B[(2 * 4 + t) * 64 + lane], acc[t], 0, 0, 0);
        acc[t] = __builtin_amdgcn_mfma_f32_16x16x32_bf16(pf1, B[(3 * 4 + t) * 64 + lane], acc[t], 0, 0, 0);
    }

    float vv[4][4], ss[4];
    #pragma unroll
    for (int r = 0; r < 4; ++r) {
        float sr = 0.f;
        #pragma unroll
        for (int t = 0; t < 4; ++t) {
            float v = acc[t][r] + lbias[16 * t + m];
            v = v >= 0.f ? v : 0.2f * v;
            vv[t][r] = v;
            sr += v * v;
        }
        ss[r] = sr;
    }
    #pragma unroll
    for (int off = 1; off < 16; off <<= 1) {
        #pragma unroll
        for (int r = 0; r < 4; ++r) ss[r] += __shfl_xor(ss[r], off, 64);
    }
    #pragma unroll
    for (int r = 0; r < 4; ++r) {
        int rw = rb + w * 16 + 4 * g2 + r;
        if (rw < NNODES) {
            float rn = 1.f / fmaxf(sqrtf(ss[r]), 1e-12f);
            #pragma unroll
            for (int t = 0; t < 4; ++t) {
                out[(size_t)rw * OSTRIDE + (layer + 1) * DIM + 16 * t + m] = vv[t][r] * rn;
                egoOut[(size_t)rw * DIM + 16 * t + m] = f2b(vv[t][r]);
            }
        }
    }
}

// ---------------------------------------------------------------------------
extern "C" void kernel_launch(void* const* d_in, const int* in_sizes, int n_in,
                              void* d_out, int out_size, void* d_ws, size_t ws_size,
                              hipStream_t stream) {
    const float* ue   = (const float*)d_in[0];
    const float* ie   = (const float*)d_in[1];
    const float* Wg   = (const float*)d_in[2];
    const float* bg   = (const float*)d_in[3];
    const float* Wb   = (const float*)d_in[4];
    const float* bb   = (const float*)d_in[5];
    const int*   rows = (const int*)d_in[6];
    const int*   cols = (const int*)d_in[7];
    const float* vals = (const float*)d_in[8];
    float* out = (float*)d_out;

    // ws layout (R17, aliasing-safe), E = NEDGES bytes-unit:
    //  [0,8E)    tmp int2 (live through bucket_build; dead after)
    //  [8E,12E)  colS int[E]      <- bucket_build output (disjoint from tmp)
    //  [12E,14E) valS u16[E]      <- bucket_build output
    //  [0,4E)    egoA u16[N*64]   (aliases dead tmp, created by init_ego)
    //  [4E,8E)   egoB u16[N*64]
    //  [14E..)   rs | bcount | bbase | bcursor | wpre
    char* base = (char*)d_ws;
    const size_t E = NEDGES;
    int2* tmp  = (int2*)base;
    int*  colS = (int*)(base + 8 * E);
    u16*  valS = (u16*)(base + 12 * E);
    u16*  egoA = (u16*)base;
    u16*  egoB = (u16*)(base + 4 * E);
    int*  rs     = (int*)(base + 14 * E);
    int*  bcount  = rs + NNODES + 1;
    int*  bbase   = bcount + NBUCK;
    int*  bcursor = bbase + NBUCK + 1;
    u16*  wpre    = (u16*)(bcursor + NBUCK);

    hipMemsetAsync(bcount, 0, NBUCK * sizeof(int), stream);
    bucket_count<<<NPBLK, 256, 0, stream>>>(rows, bcount);
    bucket_scan<<<1, 512, 0, stream>>>(bcount, bbase, bcursor);
    bucket_place<<<NPBLK, 256, 0, stream>>>(rows, cols, vals, bcursor, tmp);
    bucket_build<<<NBUCK, 256, 0, stream>>>(bbase, tmp, rs, colS, valS);

    weights_prep<<<dim3(32, 3), 256, 0, stream>>>(Wg, Wb, wpre);

    // init_ego AFTER bucket_build: egoA aliases dead tmp region
    init_ego<<<(NNODES * 16 + 255) / 256, 256, 0, stream>>>(ue, ie, out, (u32*)egoA);

    u16* ei = egoA; u16* eo = egoB;
    for (int l = 0; l < 3; ++l) {
        fused_layer<<<(NNODES + 63) / 64, 256, 0, stream>>>(rs, colS, valS, ei, eo,
                                                            out, wpre, bg, bb, l);
        u16* t = ei; ei = eo; eo = t;
    }
}

// Round 18
// 360.254 us; speedup vs baseline: 1.2813x; 1.0588x over previous
//
#include <hip/hip_runtime.h>
#include <hip/hip_bf16.h>

#define NUSERS  50000
#define NNODES  100000
#define NEDGES  3200000
#define DIM     64
#define OSTRIDE 256   // output row stride: (3+1)*64
#define NBUCK   391   // ceil(NNODES/256): 256-row buckets
#define EPB     8192  // edges per block in bucketing kernels
#define NPBLK   391
#define NCOLB   391   // col>>8 bins
#define BCAP    8704  // max edges per 256-row bucket (mean 8192, +5.7 sigma)
#define LSTR2   72    // u16 stride of LDS side tile: 144B/row, 16B-aligned

typedef unsigned short u16;
typedef unsigned int u32;
typedef __attribute__((ext_vector_type(8))) short bf16x8;
typedef __attribute__((ext_vector_type(4))) float f32x4;

__device__ __forceinline__ float us2f(u16 u) {
    return __uint_as_float((u32)u << 16);
}
__device__ __forceinline__ u16 f2b(float f) {           // f32 -> bf16 RNE bits
    u32 u = __float_as_uint(f);
    return (u16)((u + 0x7fffu + ((u >> 16) & 1u)) >> 16);
}

// ---------------------------------------------------------------------------
// out[:, 0:64] = concat(ue, ie) (fp32); ego[N][64] bf16
// ---------------------------------------------------------------------------
__global__ __launch_bounds__(256) void init_ego(const float* __restrict__ ue,
                                                const float* __restrict__ ie,
                                                float* __restrict__ out,
                                                u32*   __restrict__ ego32) {
    int gid = blockIdx.x * 256 + threadIdx.x;
    if (gid >= NNODES * 16) return;
    int node = gid >> 4, c = gid & 15;
    float4 v = (node < NUSERS)
        ? ((const float4*)ue)[node * 16 + c]
        : ((const float4*)ie)[(size_t)(node - NUSERS) * 16 + c];
    ((float4*)(out + (size_t)node * OSTRIDE))[c] = v;
    u32* d = ego32 + (size_t)node * 32 + 2 * c;
    d[0] = (u32)f2b(v.x) | ((u32)f2b(v.y) << 16);
    d[1] = (u32)f2b(v.z) | ((u32)f2b(v.w) << 16);
}

// ---------------------------------------------------------------------------
// Pass 1: counting sort by row>>8 into 256-row buckets (R11-proven, 391 blk)
// ---------------------------------------------------------------------------
__global__ __launch_bounds__(256) void bucket_count(const int* __restrict__ rows,
                                                    int* __restrict__ bcount) {
    __shared__ int lh[NBUCK];
    int tid = threadIdx.x;
    for (int i = tid; i < NBUCK; i += 256) lh[i] = 0;
    __syncthreads();
    int e0 = blockIdx.x * EPB, e1 = min(e0 + EPB, NEDGES);
    for (int e = e0 + tid; e < e1; e += 256)
        atomicAdd(&lh[rows[e] >> 8], 1);
    __syncthreads();
    for (int i = tid; i < NBUCK; i += 256)
        if (lh[i]) atomicAdd(&bcount[i], lh[i]);
}

__global__ __launch_bounds__(512) void bucket_scan(const int* __restrict__ bcount,
                                                   int* __restrict__ bbase,
                                                   int* __restrict__ bcursor) {
    __shared__ int sc[512];
    int tid = threadIdx.x;
    int v = (tid < NBUCK) ? bcount[tid] : 0;
    sc[tid] = v;
    __syncthreads();
    for (int off = 1; off < 512; off <<= 1) {
        int t = (tid >= off) ? sc[tid - off] : 0;
        __syncthreads();
        sc[tid] += t;
        __syncthreads();
    }
    if (tid < NBUCK) {
        int excl = sc[tid] - v;
        bbase[tid] = excl;
        bcursor[tid] = excl;
    }
    if (tid == 0) bbase[NBUCK] = NEDGES;
}

__global__ __launch_bounds__(256) void bucket_place(const int*   __restrict__ rows,
                                                    const int*   __restrict__ cols,
                                                    const float* __restrict__ vals,
                                                    int*  __restrict__ bcursor,
                                                    int2* __restrict__ tmp) {
    __shared__ int lh[NBUCK];
    int tid = threadIdx.x;
    for (int i = tid; i < NBUCK; i += 256) lh[i] = 0;
    __syncthreads();
    int e0 = blockIdx.x * EPB, e1 = min(e0 + EPB, NEDGES);
    for (int e = e0 + tid; e < e1; e += 256)
        atomicAdd(&lh[rows[e] >> 8], 1);
    __syncthreads();
    for (int i = tid; i < NBUCK; i += 256) {
        int c = lh[i];
        lh[i] = c ? atomicAdd(&bcursor[i], c) : 0;
    }
    __syncthreads();
    for (int e = e0 + tid; e < e1; e += 256) {
        int r = rows[e];
        int p = atomicAdd(&lh[r >> 8], 1);
        tmp[p] = make_int2(((r & 255) << 20) | cols[e], (int)f2b(vals[e]));
    }
}

// ---------------------------------------------------------------------------
// Pass 2+3 merged (R17-proven): stage in LDS by colbin, emit CSR directly.
// ---------------------------------------------------------------------------
__global__ __launch_bounds__(256) void bucket_build(const int*  __restrict__ bbase,
                                                    const int2* __restrict__ tmp,
                                                    int* __restrict__ rs,
                                                    int* __restrict__ colS,
                                                    u16* __restrict__ valS) {
    __shared__ int cnt[NCOLB];
    __shared__ int tsum[256];
    __shared__ int rcnt[256];
    __shared__ int cur[256];
    __shared__ u32 colL[BCAP];   // 34 KB
    __shared__ u16 valL[BCAP];   // 17 KB

    int b = blockIdx.x, tid = threadIdx.x;
    int j0 = bbase[b], j1 = bbase[b + 1];
    int n = j1 - j0;

    for (int i = tid; i < NCOLB; i += 256) cnt[i] = 0;
    rcnt[tid] = 0;
    __syncthreads();
    for (int j = j0 + tid; j < j1; j += 256)
        atomicAdd(&cnt[(tmp[j].x & 0xFFFFF) >> 8], 1);
    __syncthreads();
    int i0 = 2 * tid, i1 = i0 + 1;
    int c0 = (i0 < NCOLB) ? cnt[i0] : 0;
    int c1 = (i1 < NCOLB) ? cnt[i1] : 0;
    int tot = c0 + c1;
    tsum[tid] = tot;
    __syncthreads();
    for (int off = 1; off < 256; off <<= 1) {
        int t = (tid >= off) ? tsum[tid - off] : 0;
        __syncthreads();
        tsum[tid] += t;
        __syncthreads();
    }
    int run = tsum[tid] - tot;
    if (i0 < NCOLB) { cnt[i0] = run; run += c0; }
    if (i1 < NCOLB) cnt[i1] = run;
    __syncthreads();
    for (int j = j0 + tid; j < j1; j += 256) {
        int2 t2 = tmp[j];
        int q = atomicAdd(&cnt[(t2.x & 0xFFFFF) >> 8], 1);
        if (q < BCAP) { colL[q] = (u32)t2.x; valL[q] = (u16)t2.y; }
        atomicAdd(&rcnt[((u32)t2.x) >> 20], 1);
    }
    __syncthreads();
    int own = rcnt[tid];
    for (int off = 1; off < 256; off <<= 1) {
        int t = (tid >= off) ? rcnt[tid - off] : 0;
        __syncthreads();
        rcnt[tid] += t;
        __syncthreads();
    }
    int start = rcnt[tid] - own;
    int row = b * 256 + tid;
    if (row < NNODES) rs[row] = j0 + start;
    if (b == 0 && tid == 0) rs[NNODES] = NEDGES;
    cur[tid] = start;
    __syncthreads();
    for (int i = tid; i < n && i < BCAP; i += 256) {
        u32 cx = colL[i];
        int p = j0 + atomicAdd(&cur[cx >> 20], 1);
        colS[p] = cx & 0xFFFFF;
        valS[p] = valL[i];
    }
}

// ---------------------------------------------------------------------------
// Pre-convert weights to fragment-ordered bf16 (R7, proven)
// ---------------------------------------------------------------------------
__global__ __launch_bounds__(256) void weights_prep(const float* __restrict__ Wg,
                                                    const float* __restrict__ Wb,
                                                    u16* __restrict__ wpre) {
    int layer = blockIdx.y;
    int idx = blockIdx.x * 256 + threadIdx.x;   // 0..8191
    int e = idx & 7, l = (idx >> 3) & 63, t = (idx >> 9) & 3, s = idx >> 11;
    int k = 32 * s + 8 * (l >> 4) + e;
    int n = 16 * t + (l & 15);
    float wv = (k < 64) ? Wg[layer * 4096 + k * 64 + n]
                        : Wb[layer * 4096 + (k - 64) * 64 + n];
    wpre[layer * 8192 + idx] = f2b(wv);
}

// ---------------------------------------------------------------------------
// Fused layer (R18): LDS = side tile ONLY (9.2KB). Weights + biases read
// directly from global (L2-resident, 1KB-contiguous per fragment load).
// Tests whether the 26KB LDS block was the 41%-occupancy cap.
// ---------------------------------------------------------------------------
__global__ __launch_bounds__(256, 6) void fused_layer(const int* __restrict__ rs,
                                                      const int* __restrict__ colS,
                                                      const u16* __restrict__ valS,
                                                      const u16* __restrict__ egoIn,
                                                      u16*       __restrict__ egoOut,
                                                      float*     __restrict__ out,
                                                      const u16* __restrict__ wpre,
                                                      const float* __restrict__ bg,
                                                      const float* __restrict__ bb,
                                                      int layer) {
    __shared__ u16 sideL[64 * LSTR2];   // 9.2 KB (only LDS in kernel)

    int tid = threadIdx.x;
    int w = tid >> 6, lane = tid & 63;
    int grp = lane >> 4, d = lane & 15;
    const uint2* ego64 = (const uint2*)egoIn;
    int rb = blockIdx.x * 64;

    // ---- Phase A: gather SpMM into LDS side tile ----
    #pragma unroll
    for (int sub = 0; sub < 4; ++sub) {
        int lr = sub * 16 + w * 4 + grp;
        int row = rb + lr;
        if (row < NNODES) {
            int j0 = rs[row], j1 = rs[row + 1];
            float a0 = 0.f, a1 = 0.f, a2 = 0.f, a3 = 0.f;
            float b0 = 0.f, b1 = 0.f, b2 = 0.f, b3 = 0.f;
            int j = j0;
            for (; j + 8 <= j1; j += 8) {
                int   c[8]; float v[8]; uint2 gg[8];
                #pragma unroll
                for (int s = 0; s < 8; ++s) { c[s] = colS[j + s]; v[s] = us2f(valS[j + s]); }
                #pragma unroll
                for (int s = 0; s < 8; ++s) gg[s] = ego64[(size_t)c[s] * 16 + d];
                #pragma unroll
                for (int s = 0; s < 8; ++s) {
                    if (s & 1) {
                        b0 = fmaf(v[s], __uint_as_float(gg[s].x << 16),         b0);
                        b1 = fmaf(v[s], __uint_as_float(gg[s].x & 0xFFFF0000u), b1);
                        b2 = fmaf(v[s], __uint_as_float(gg[s].y << 16),         b2);
                        b3 = fmaf(v[s], __uint_as_float(gg[s].y & 0xFFFF0000u), b3);
                    } else {
                        a0 = fmaf(v[s], __uint_as_float(gg[s].x << 16),         a0);
                        a1 = fmaf(v[s], __uint_as_float(gg[s].x & 0xFFFF0000u), a1);
                        a2 = fmaf(v[s], __uint_as_float(gg[s].y << 16),         a2);
                        a3 = fmaf(v[s], __uint_as_float(gg[s].y & 0xFFFF0000u), a3);
                    }
                }
            }
            for (; j < j1; ++j) {
                int cc = colS[j];
                float vv = us2f(valS[j]);
                uint2 gg = ego64[(size_t)cc * 16 + d];
                a0 = fmaf(vv, __uint_as_float(gg.x << 16),         a0);
                a1 = fmaf(vv, __uint_as_float(gg.x & 0xFFFF0000u), a1);
                a2 = fmaf(vv, __uint_as_float(gg.y << 16),         a2);
                a3 = fmaf(vv, __uint_as_float(gg.y & 0xFFFF0000u), a3);
            }
            a0 += b0; a1 += b1; a2 += b2; a3 += b3;
            uint2 o;
            o.x = (u32)f2b(a0) | ((u32)f2b(a1) << 16);
            o.y = (u32)f2b(a2) | ((u32)f2b(a3) << 16);
            *(uint2*)&sideL[lr * LSTR2 + 4 * d] = o;   // dims 4d..4d+3
        }
    }
    __syncthreads();

    // ---- Phase B: MFMA dense + bias + leaky-relu + fused normalize ----
    int g2 = lane >> 4, m = lane & 15;
    int lrB = w * 16 + m;
    int rowc = min(rb + lrB, NNODES - 1);

    bf16x8 sf0 = *(const bf16x8*)&sideL[lrB * LSTR2 + g2 * 8];
    bf16x8 sf1 = *(const bf16x8*)&sideL[lrB * LSTR2 + 32 + g2 * 8];
    bf16x8 ef0 = *(const bf16x8*)(egoIn + (size_t)rowc * DIM + g2 * 8);
    bf16x8 ef1 = *(const bf16x8*)(egoIn + (size_t)rowc * DIM + 32 + g2 * 8);
    bf16x8 pf0, pf1;
    #pragma unroll
    for (int e = 0; e < 8; ++e) {
        pf0[e] = (short)f2b(us2f((u16)ef0[e]) * us2f((u16)sf0[e]));
        pf1[e] = (short)f2b(us2f((u16)ef1[e]) * us2f((u16)sf1[e]));
    }

    const bf16x8* B = (const bf16x8*)(wpre + layer * 8192);   // global, L2-hot
    f32x4 acc[4];
    #pragma unroll
    for (int t = 0; t < 4; ++t) {
        acc[t] = (f32x4){0.f, 0.f, 0.f, 0.f};
        acc[t] = __builtin_amdgcn_mfma_f32_16x16x32_bf16(sf0, B[(0 * 4 + t) * 64 + lane], acc[t], 0, 0, 0);
        acc[t] = __builtin_amdgcn_mfma_f32_16x16x32_bf16(sf1, B[(1 * 4 + t) * 64 + lane], acc[t], 0, 0, 0);
        acc[t] = __builtin_amdgcn_mfma_f32_16x16x32_bf16(pf0, B[(2 * 4 + t) * 64 + lane], acc[t], 0, 0, 0);
        acc[t] = __builtin_amdgcn_mfma_f32_16x16x32_bf16(pf1, B[(3 * 4 + t) * 64 + lane], acc[t], 0, 0, 0);
    }

    float vv[4][4], ss[4];
    #pragma unroll
    for (int r = 0; r < 4; ++r) {
        float sr = 0.f;
        #pragma unroll
        for (int t = 0; t < 4; ++t) {
            float v = acc[t][r] + bg[layer * 64 + 16 * t + m] + bb[layer * 64 + 16 * t + m];
            v = v >= 0.f ? v : 0.2f * v;
            vv[t][r] = v;
            sr += v * v;
        }
        ss[r] = sr;
    }
    #pragma unroll
    for (int off = 1; off < 16; off <<= 1) {
        #pragma unroll
        for (int r = 0; r < 4; ++r) ss[r] += __shfl_xor(ss[r], off, 64);
    }
    #pragma unroll
    for (int r = 0; r < 4; ++r) {
        int rw = rb + w * 16 + 4 * g2 + r;
        if (rw < NNODES) {
            float rn = 1.f / fmaxf(sqrtf(ss[r]), 1e-12f);
            #pragma unroll
            for (int t = 0; t < 4; ++t) {
                out[(size_t)rw * OSTRIDE + (layer + 1) * DIM + 16 * t + m] = vv[t][r] * rn;
                egoOut[(size_t)rw * DIM + 16 * t + m] = f2b(vv[t][r]);
            }
        }
    }
}

// ---------------------------------------------------------------------------
extern "C" void kernel_launch(void* const* d_in, const int* in_sizes, int n_in,
                              void* d_out, int out_size, void* d_ws, size_t ws_size,
                              hipStream_t stream) {
    const float* ue   = (const float*)d_in[0];
    const float* ie   = (const float*)d_in[1];
    const float* Wg   = (const float*)d_in[2];
    const float* bg   = (const float*)d_in[3];
    const float* Wb   = (const float*)d_in[4];
    const float* bb   = (const float*)d_in[5];
    const int*   rows = (const int*)d_in[6];
    const int*   cols = (const int*)d_in[7];
    const float* vals = (const float*)d_in[8];
    float* out = (float*)d_out;

    // ws layout (R17-proven, aliasing-safe), E = NEDGES:
    //  [0,8E)    tmp int2 (live through bucket_build; dead after)
    //  [8E,12E)  colS int[E]
    //  [12E,14E) valS u16[E]
    //  [0,4E)    egoA u16[N*64] (aliases dead tmp after build)
    //  [4E,8E)   egoB u16[N*64]
    //  [14E..)   rs | bcount | bbase | bcursor | wpre
    char* base = (char*)d_ws;
    const size_t E = NEDGES;
    int2* tmp  = (int2*)base;
    int*  colS = (int*)(base + 8 * E);
    u16*  valS = (u16*)(base + 12 * E);
    u16*  egoA = (u16*)base;
    u16*  egoB = (u16*)(base + 4 * E);
    int*  rs     = (int*)(base + 14 * E);
    int*  bcount  = rs + NNODES + 1;
    int*  bbase   = bcount + NBUCK;
    int*  bcursor = bbase + NBUCK + 1;
    u16*  wpre    = (u16*)(bcursor + NBUCK);

    hipMemsetAsync(bcount, 0, NBUCK * sizeof(int), stream);
    bucket_count<<<NPBLK, 256, 0, stream>>>(rows, bcount);
    bucket_scan<<<1, 512, 0, stream>>>(bcount, bbase, bcursor);
    bucket_place<<<NPBLK, 256, 0, stream>>>(rows, cols, vals, bcursor, tmp);
    bucket_build<<<NBUCK, 256, 0, stream>>>(bbase, tmp, rs, colS, valS);

    weights_prep<<<dim3(32, 3), 256, 0, stream>>>(Wg, Wb, wpre);

    // init_ego AFTER bucket_build: egoA aliases dead tmp region
    init_ego<<<(NNODES * 16 + 255) / 256, 256, 0, stream>>>(ue, ie, out, (u32*)egoA);

    u16* ei = egoA; u16* eo = egoB;
    for (int l = 0; l < 3; ++l) {
        fused_layer<<<(NNODES + 63) / 64, 256, 0, stream>>>(rs, colS, valS, ei, eo,
                                                            out, wpre, bg, bb, l);
        u16* t = ei; ei = eo; eo = t;
    }
}

// Round 19
// 294.158 us; speedup vs baseline: 1.5692x; 1.2247x over previous
//
#include <hip/hip_runtime.h>
#include <hip/hip_bf16.h>

#define NUSERS  50000
#define NNODES  100000
#define NEDGES  3200000
#define DIM     64
#define OSTRIDE 256   // output row stride: (3+1)*64
#define NBUCK   391   // ceil(NNODES/256): 256-row buckets
#define EPB     8192  // edges per block in bucketing kernels
#define NPBLK   391
#define NCOLB   391   // col>>8 bins
#define BCAP    8704  // max edges per 256-row bucket (mean 8192, +5.7 sigma)
#define LSTR2   72    // u16 stride of LDS side tile: 144B/row, 16B-aligned

typedef unsigned short u16;
typedef unsigned int u32;
typedef __attribute__((ext_vector_type(8))) short bf16x8;
typedef __attribute__((ext_vector_type(4))) float f32x4;

__device__ __forceinline__ float us2f(u16 u) {
    return __uint_as_float((u32)u << 16);
}
__device__ __forceinline__ u16 f2b(float f) {           // f32 -> bf16 RNE bits
    u32 u = __float_as_uint(f);
    return (u16)((u + 0x7fffu + ((u >> 16) & 1u)) >> 16);
}

// ---------------------------------------------------------------------------
// out[:, 0:64] = concat(ue, ie) (fp32); ego[N][64] bf16
// ---------------------------------------------------------------------------
__global__ __launch_bounds__(256) void init_ego(const float* __restrict__ ue,
                                                const float* __restrict__ ie,
                                                float* __restrict__ out,
                                                u32*   __restrict__ ego32) {
    int gid = blockIdx.x * 256 + threadIdx.x;
    if (gid >= NNODES * 16) return;
    int node = gid >> 4, c = gid & 15;
    float4 v = (node < NUSERS)
        ? ((const float4*)ue)[node * 16 + c]
        : ((const float4*)ie)[(size_t)(node - NUSERS) * 16 + c];
    ((float4*)(out + (size_t)node * OSTRIDE))[c] = v;
    u32* d = ego32 + (size_t)node * 32 + 2 * c;
    d[0] = (u32)f2b(v.x) | ((u32)f2b(v.y) << 16);
    d[1] = (u32)f2b(v.z) | ((u32)f2b(v.w) << 16);
}

// ---------------------------------------------------------------------------
// Pass 1a: bucket histogram (row>>8), 8-deep unrolled
// ---------------------------------------------------------------------------
__global__ __launch_bounds__(256) void bucket_count(const int* __restrict__ rows,
                                                    int* __restrict__ bcount) {
    __shared__ int lh[NBUCK];
    int tid = threadIdx.x;
    for (int i = tid; i < NBUCK; i += 256) lh[i] = 0;
    __syncthreads();
    int e0 = blockIdx.x * EPB, e1 = min(e0 + EPB, NEDGES);
    int e = e0 + tid;
    for (; e + 1792 < e1; e += 2048) {
        int r[8];
        #pragma unroll
        for (int s = 0; s < 8; ++s) r[s] = rows[e + s * 256];
        #pragma unroll
        for (int s = 0; s < 8; ++s) atomicAdd(&lh[r[s] >> 8], 1);
    }
    for (; e < e1; e += 256) atomicAdd(&lh[rows[e] >> 8], 1);
    __syncthreads();
    for (int i = tid; i < NBUCK; i += 256)
        if (lh[i]) atomicAdd(&bcount[i], lh[i]);
}

__global__ __launch_bounds__(512) void bucket_scan(const int* __restrict__ bcount,
                                                   int* __restrict__ bbase,
                                                   int* __restrict__ bcursor) {
    __shared__ int sc[512];
    int tid = threadIdx.x;
    int v = (tid < NBUCK) ? bcount[tid] : 0;
    sc[tid] = v;
    __syncthreads();
    for (int off = 1; off < 512; off <<= 1) {
        int t = (tid >= off) ? sc[tid - off] : 0;
        __syncthreads();
        sc[tid] += t;
        __syncthreads();
    }
    if (tid < NBUCK) {
        int excl = sc[tid] - v;
        bbase[tid] = excl;
        bcursor[tid] = excl;
    }
    if (tid == 0) bbase[NBUCK] = NEDGES;
}

// ---------------------------------------------------------------------------
// Pass 1b: place, 8-deep unrolled (8 independent atomic->store chains/thread)
// ---------------------------------------------------------------------------
__global__ __launch_bounds__(256) void bucket_place(const int*   __restrict__ rows,
                                                    const int*   __restrict__ cols,
                                                    const float* __restrict__ vals,
                                                    int*  __restrict__ bcursor,
                                                    int2* __restrict__ tmp) {
    __shared__ int lh[NBUCK];
    int tid = threadIdx.x;
    for (int i = tid; i < NBUCK; i += 256) lh[i] = 0;
    __syncthreads();
    int e0 = blockIdx.x * EPB, e1 = min(e0 + EPB, NEDGES);
    int e = e0 + tid;
    for (; e + 1792 < e1; e += 2048) {
        int r[8];
        #pragma unroll
        for (int s = 0; s < 8; ++s) r[s] = rows[e + s * 256];
        #pragma unroll
        for (int s = 0; s < 8; ++s) atomicAdd(&lh[r[s] >> 8], 1);
    }
    for (; e < e1; e += 256) atomicAdd(&lh[rows[e] >> 8], 1);
    __syncthreads();
    for (int i = tid; i < NBUCK; i += 256) {
        int c = lh[i];
        lh[i] = c ? atomicAdd(&bcursor[i], c) : 0;
    }
    __syncthreads();
    e = e0 + tid;
    for (; e + 1792 < e1; e += 2048) {
        int r[8], cc[8]; float vv[8];
        #pragma unroll
        for (int s = 0; s < 8; ++s) r[s] = rows[e + s * 256];
        int p[8];
        #pragma unroll
        for (int s = 0; s < 8; ++s) p[s] = atomicAdd(&lh[r[s] >> 8], 1);
        #pragma unroll
        for (int s = 0; s < 8; ++s) { cc[s] = cols[e + s * 256]; vv[s] = vals[e + s * 256]; }
        #pragma unroll
        for (int s = 0; s < 8; ++s)
            tmp[p[s]] = make_int2(((r[s] & 255) << 20) | cc[s], (int)f2b(vv[s]));
    }
    for (; e < e1; e += 256) {
        int r = rows[e];
        int p = atomicAdd(&lh[r >> 8], 1);
        tmp[p] = make_int2(((r & 255) << 20) | cols[e], (int)f2b(vals[e]));
    }
}

// ---------------------------------------------------------------------------
// Pass 2+3 merged: stage in LDS by colbin, emit CSR as merged u32
// cv = (val_bf16_sans_sign:15 << 17) | col:17   (vals are non-negative)
// ---------------------------------------------------------------------------
__global__ __launch_bounds__(256) void bucket_build(const int*  __restrict__ bbase,
                                                    const int2* __restrict__ tmp,
                                                    int* __restrict__ rs,
                                                    u32* __restrict__ cvS) {
    __shared__ int cnt[NCOLB];
    __shared__ int tsum[256];
    __shared__ int rcnt[256];
    __shared__ int cur[256];
    __shared__ u32 colL[BCAP];   // 34 KB
    __shared__ u16 valL[BCAP];   // 17 KB

    int b = blockIdx.x, tid = threadIdx.x;
    int j0 = bbase[b], j1 = bbase[b + 1];
    int n = j1 - j0;

    for (int i = tid; i < NCOLB; i += 256) cnt[i] = 0;
    rcnt[tid] = 0;
    __syncthreads();
    for (int j = j0 + tid; j < j1; j += 256)
        atomicAdd(&cnt[(tmp[j].x & 0xFFFFF) >> 8], 1);
    __syncthreads();
    int i0 = 2 * tid, i1 = i0 + 1;
    int c0 = (i0 < NCOLB) ? cnt[i0] : 0;
    int c1 = (i1 < NCOLB) ? cnt[i1] : 0;
    int tot = c0 + c1;
    tsum[tid] = tot;
    __syncthreads();
    for (int off = 1; off < 256; off <<= 1) {
        int t = (tid >= off) ? tsum[tid - off] : 0;
        __syncthreads();
        tsum[tid] += t;
        __syncthreads();
    }
    int run = tsum[tid] - tot;
    if (i0 < NCOLB) { cnt[i0] = run; run += c0; }
    if (i1 < NCOLB) cnt[i1] = run;
    __syncthreads();
    for (int j = j0 + tid; j < j1; j += 256) {
        int2 t2 = tmp[j];
        int q = atomicAdd(&cnt[(t2.x & 0xFFFFF) >> 8], 1);
        if (q < BCAP) { colL[q] = (u32)t2.x; valL[q] = (u16)t2.y; }
        atomicAdd(&rcnt[((u32)t2.x) >> 20], 1);
    }
    __syncthreads();
    int own = rcnt[tid];
    for (int off = 1; off < 256; off <<= 1) {
        int t = (tid >= off) ? rcnt[tid - off] : 0;
        __syncthreads();
        rcnt[tid] += t;
        __syncthreads();
    }
    int start = rcnt[tid] - own;
    int row = b * 256 + tid;
    if (row < NNODES) rs[row] = j0 + start;
    if (b == 0 && tid == 0) rs[NNODES] = NEDGES;
    cur[tid] = start;
    __syncthreads();
    for (int i = tid; i < n && i < BCAP; i += 256) {
        u32 cx = colL[i];
        int p = j0 + atomicAdd(&cur[cx >> 20], 1);
        cvS[p] = ((u32)valL[i] << 17) | (cx & 0x1FFFF);
    }
}

// ---------------------------------------------------------------------------
// Pre-convert weights to fragment-ordered bf16 (R7, proven)
// ---------------------------------------------------------------------------
__global__ __launch_bounds__(256) void weights_prep(const float* __restrict__ Wg,
                                                    const float* __restrict__ Wb,
                                                    u16* __restrict__ wpre) {
    int layer = blockIdx.y;
    int idx = blockIdx.x * 256 + threadIdx.x;   // 0..8191
    int e = idx & 7, l = (idx >> 3) & 63, t = (idx >> 9) & 3, s = idx >> 11;
    int k = 32 * s + 8 * (l >> 4) + e;
    int n = 16 * t + (l & 15);
    float wv = (k < 64) ? Wg[layer * 4096 + k * 64 + n]
                        : Wb[layer * 4096 + (k - 64) * 64 + n];
    wpre[layer * 8192 + idx] = f2b(wv);
}

// ---------------------------------------------------------------------------
// Fused layer (R18 body + merged-cv CSR): Phase A gather SpMM into LDS side
// tile (1 metadata load/edge); Phase B MFMA dense + bias + leaky-relu +
// fused L2-normalize, weights/biases straight from global (L2-hot).
// ---------------------------------------------------------------------------
__global__ __launch_bounds__(256, 6) void fused_layer(const int* __restrict__ rs,
                                                      const u32* __restrict__ cvS,
                                                      const u16* __restrict__ egoIn,
                                                      u16*       __restrict__ egoOut,
                                                      float*     __restrict__ out,
                                                      const u16* __restrict__ wpre,
                                                      const float* __restrict__ bg,
                                                      const float* __restrict__ bb,
                                                      int layer) {
    __shared__ u16 sideL[64 * LSTR2];   // 9.2 KB (only LDS in kernel)

    int tid = threadIdx.x;
    int w = tid >> 6, lane = tid & 63;
    int grp = lane >> 4, d = lane & 15;
    const uint2* ego64 = (const uint2*)egoIn;
    int rb = blockIdx.x * 64;

    // ---- Phase A: gather SpMM into LDS side tile ----
    #pragma unroll
    for (int sub = 0; sub < 4; ++sub) {
        int lr = sub * 16 + w * 4 + grp;
        int row = rb + lr;
        if (row < NNODES) {
            int j0 = rs[row], j1 = rs[row + 1];
            float a0 = 0.f, a1 = 0.f, a2 = 0.f, a3 = 0.f;
            float b0 = 0.f, b1 = 0.f, b2 = 0.f, b3 = 0.f;
            int j = j0;
            for (; j + 8 <= j1; j += 8) {
                u32 cv[8]; uint2 gg[8];
                #pragma unroll
                for (int s = 0; s < 8; ++s) cv[s] = cvS[j + s];
                #pragma unroll
                for (int s = 0; s < 8; ++s)
                    gg[s] = ego64[(size_t)(cv[s] & 0x1FFFF) * 16 + d];
                #pragma unroll
                for (int s = 0; s < 8; ++s) {
                    float v = __uint_as_float((cv[s] >> 1) & 0xFFFF0000u);
                    if (s & 1) {
                        b0 = fmaf(v, __uint_as_float(gg[s].x << 16),         b0);
                        b1 = fmaf(v, __uint_as_float(gg[s].x & 0xFFFF0000u), b1);
                        b2 = fmaf(v, __uint_as_float(gg[s].y << 16),         b2);
                        b3 = fmaf(v, __uint_as_float(gg[s].y & 0xFFFF0000u), b3);
                    } else {
                        a0 = fmaf(v, __uint_as_float(gg[s].x << 16),         a0);
                        a1 = fmaf(v, __uint_as_float(gg[s].x & 0xFFFF0000u), a1);
                        a2 = fmaf(v, __uint_as_float(gg[s].y << 16),         a2);
                        a3 = fmaf(v, __uint_as_float(gg[s].y & 0xFFFF0000u), a3);
                    }
                }
            }
            for (; j < j1; ++j) {
                u32 cv = cvS[j];
                float v = __uint_as_float((cv >> 1) & 0xFFFF0000u);
                uint2 gg = ego64[(size_t)(cv & 0x1FFFF) * 16 + d];
                a0 = fmaf(v, __uint_as_float(gg.x << 16),         a0);
                a1 = fmaf(v, __uint_as_float(gg.x & 0xFFFF0000u), a1);
                a2 = fmaf(v, __uint_as_float(gg.y << 16),         a2);
                a3 = fmaf(v, __uint_as_float(gg.y & 0xFFFF0000u), a3);
            }
            a0 += b0; a1 += b1; a2 += b2; a3 += b3;
            uint2 o;
            o.x = (u32)f2b(a0) | ((u32)f2b(a1) << 16);
            o.y = (u32)f2b(a2) | ((u32)f2b(a3) << 16);
            *(uint2*)&sideL[lr * LSTR2 + 4 * d] = o;   // dims 4d..4d+3
        }
    }
    __syncthreads();

    // ---- Phase B: MFMA dense + bias + leaky-relu + fused normalize ----
    int g2 = lane >> 4, m = lane & 15;
    int lrB = w * 16 + m;
    int rowc = min(rb + lrB, NNODES - 1);

    bf16x8 sf0 = *(const bf16x8*)&sideL[lrB * LSTR2 + g2 * 8];
    bf16x8 sf1 = *(const bf16x8*)&sideL[lrB * LSTR2 + 32 + g2 * 8];
    bf16x8 ef0 = *(const bf16x8*)(egoIn + (size_t)rowc * DIM + g2 * 8);
    bf16x8 ef1 = *(const bf16x8*)(egoIn + (size_t)rowc * DIM + 32 + g2 * 8);
    bf16x8 pf0, pf1;
    #pragma unroll
    for (int e = 0; e < 8; ++e) {
        pf0[e] = (short)f2b(us2f((u16)ef0[e]) * us2f((u16)sf0[e]));
        pf1[e] = (short)f2b(us2f((u16)ef1[e]) * us2f((u16)sf1[e]));
    }

    const bf16x8* B = (const bf16x8*)(wpre + layer * 8192);   // global, L2-hot
    f32x4 acc[4];
    #pragma unroll
    for (int t = 0; t < 4; ++t) {
        acc[t] = (f32x4){0.f, 0.f, 0.f, 0.f};
        acc[t] = __builtin_amdgcn_mfma_f32_16x16x32_bf16(sf0, B[(0 * 4 + t) * 64 + lane], acc[t], 0, 0, 0);
        acc[t] = __builtin_amdgcn_mfma_f32_16x16x32_bf16(sf1, B[(1 * 4 + t) * 64 + lane], acc[t], 0, 0, 0);
        acc[t] = __builtin_amdgcn_mfma_f32_16x16x32_bf16(pf0, B[(2 * 4 + t) * 64 + lane], acc[t], 0, 0, 0);
        acc[t] = __builtin_amdgcn_mfma_f32_16x16x32_bf16(pf1, B[(3 * 4 + t) * 64 + lane], acc[t], 0, 0, 0);
    }

    float vv[4][4], ss[4];
    #pragma unroll
    for (int r = 0; r < 4; ++r) {
        float sr = 0.f;
        #pragma unroll
        for (int t = 0; t < 4; ++t) {
            float v = acc[t][r] + bg[layer * 64 + 16 * t + m] + bb[layer * 64 + 16 * t + m];
            v = v >= 0.f ? v : 0.2f * v;
            vv[t][r] = v;
            sr += v * v;
        }
        ss[r] = sr;
    }
    #pragma unroll
    for (int off = 1; off < 16; off <<= 1) {
        #pragma unroll
        for (int r = 0; r < 4; ++r) ss[r] += __shfl_xor(ss[r], off, 64);
    }
    #pragma unroll
    for (int r = 0; r < 4; ++r) {
        int rw = rb + w * 16 + 4 * g2 + r;
        if (rw < NNODES) {
            float rn = 1.f / fmaxf(sqrtf(ss[r]), 1e-12f);
            #pragma unroll
            for (int t = 0; t < 4; ++t) {
                out[(size_t)rw * OSTRIDE + (layer + 1) * DIM + 16 * t + m] = vv[t][r] * rn;
                egoOut[(size_t)rw * DIM + 16 * t + m] = f2b(vv[t][r]);
            }
        }
    }
}

// ---------------------------------------------------------------------------
extern "C" void kernel_launch(void* const* d_in, const int* in_sizes, int n_in,
                              void* d_out, int out_size, void* d_ws, size_t ws_size,
                              hipStream_t stream) {
    const float* ue   = (const float*)d_in[0];
    const float* ie   = (const float*)d_in[1];
    const float* Wg   = (const float*)d_in[2];
    const float* bg   = (const float*)d_in[3];
    const float* Wb   = (const float*)d_in[4];
    const float* bb   = (const float*)d_in[5];
    const int*   rows = (const int*)d_in[6];
    const int*   cols = (const int*)d_in[7];
    const float* vals = (const float*)d_in[8];
    float* out = (float*)d_out;

    // ws layout (R19), E = NEDGES:
    //  [0,8E)    tmp int2 (live through bucket_build; dead after)
    //  [8E,12E)  cvS u32[E]  (merged col|val CSR)
    //  [0,4E)    egoA u16[N*64] (aliases dead tmp after build)
    //  [4E,8E)   egoB u16[N*64]
    //  [12E..)   rs | bcount | bbase | bcursor | wpre   (~39 MB total)
    char* base = (char*)d_ws;
    const size_t E = NEDGES;
    int2* tmp  = (int2*)base;
    u32*  cvS  = (u32*)(base + 8 * E);
    u16*  egoA = (u16*)base;
    u16*  egoB = (u16*)(base + 4 * E);
    int*  rs     = (int*)(base + 12 * E);
    int*  bcount  = rs + NNODES + 1;
    int*  bbase   = bcount + NBUCK;
    int*  bcursor = bbase + NBUCK + 1;
    u16*  wpre    = (u16*)(bcursor + NBUCK);

    hipMemsetAsync(bcount, 0, NBUCK * sizeof(int), stream);
    bucket_count<<<NPBLK, 256, 0, stream>>>(rows, bcount);
    bucket_scan<<<1, 512, 0, stream>>>(bcount, bbase, bcursor);
    bucket_place<<<NPBLK, 256, 0, stream>>>(rows, cols, vals, bcursor, tmp);
    bucket_build<<<NBUCK, 256, 0, stream>>>(bbase, tmp, rs, cvS);

    weights_prep<<<dim3(32, 3), 256, 0, stream>>>(Wg, Wb, wpre);

    // init_ego AFTER bucket_build: egoA aliases dead tmp region
    init_ego<<<(NNODES * 16 + 255) / 256, 256, 0, stream>>>(ue, ie, out, (u32*)egoA);

    u16* ei = egoA; u16* eo = egoB;
    for (int l = 0; l < 3; ++l) {
        fused_layer<<<(NNODES + 63) / 64, 256, 0, stream>>>(rs, cvS, ei, eo,
                                                            out, wpre, bg, bb, l);
        u16* t = ei; ei = eo; eo = t;
    }
}